// Round 12
// baseline (391.479 us; speedup 1.0000x reference)
//
#include <hip/hip_runtime.h>

// LGCN encoder. bf16 propagated embeddings; acc deferred to one final pass.
// SpMM: one wave per row, 8 lanes x 16B (8 bf16), 16 nnz in flight, cached
// pack loads. CSR build: slot-allocated AoS binning (uint2 key/val; key =
// rowLocal<<17 | col) -> 1-block cnt_scan -> per-HALF-bucket counting sort
// (2 blocks per 1024-row bucket, 512 rows each: contiguous disjoint pack
// ranges, single writer per line, 2x parallelism vs 1 block/bucket).

constexpr int USER_NUM = 50000;
constexpr int ITEM_NUM = 50000;
constexpr int N_NODES  = USER_NUM + ITEM_NUM;   // 100000
constexpr int EMB      = 64;
constexpr int N_LAYERS = 3;
constexpr int TOTAL    = N_NODES * EMB;         // 6,400,000
constexpr int TOTAL4   = TOTAL / 4;
constexpr int U4       = USER_NUM * EMB / 4;

constexpr int RSHIFT = 10;                      // 1024 rows per coarse bucket
constexpr int RB     = 1 << RSHIFT;
constexpr int KA = (N_NODES + RB - 1) / RB;     // 98
constexpr int KS = (USER_NUM + RB - 1) / RB;    // 49
constexpr int NBIN = 128;
constexpr int BCHUNK = 2048;
constexpr int SLOT   = 17408;                   // mean 16384 + 8 sigma

typedef int v2i __attribute__((ext_vector_type(2)));

__device__ __forceinline__ int   ntl(const int* p)   { return __builtin_nontemporal_load(p); }
__device__ __forceinline__ float ntlf(const float* p){ return __builtin_nontemporal_load(p); }
__device__ __forceinline__ uint2 ntl2u(const uint2* p) {
    v2i v = __builtin_nontemporal_load((const v2i*)p);
    uint2 r; r.x = (unsigned)v.x; r.y = (unsigned)v.y; return r;
}

__device__ __forceinline__ unsigned f2bf(float f) {
    unsigned b = __float_as_uint(f);
    return (b + 0x7fffu + ((b >> 16) & 1u)) >> 16;   // RNE
}
__device__ __forceinline__ void bf2x(unsigned u, float& a, float& b) {
    a = __uint_as_float(u << 16);
    b = __uint_as_float(u & 0xffff0000u);
}

__global__ void init_kernel(const float* __restrict__ user_emb,
                            const float* __restrict__ item_emb,
                            unsigned* __restrict__ ego2) {
    int i = blockIdx.x * blockDim.x + threadIdx.x;
    if (i >= TOTAL4) return;
    float4 v = (i < U4) ? reinterpret_cast<const float4*>(user_emb)[i]
                        : reinterpret_cast<const float4*>(item_emb)[i - U4];
    uint2 o;
    o.x = f2bf(v.x) | (f2bf(v.y) << 16);
    o.y = f2bf(v.z) | (f2bf(v.w) << 16);
    reinterpret_cast<uint2*>(ego2)[i] = o;
}

__global__ void init_tails(int* __restrict__ tailA, int* __restrict__ tailS) {
    int t = threadIdx.x;
    if (t < KA) tailA[t] = t * SLOT;
    if (t < KS) tailS[t] = t * SLOT;
}

// LDS-staged binning by row>>RSHIFT; coalesced AoS uint2 flush into slots.
__global__ void __launch_bounds__(256) bin_alloc(
    const int* __restrict__ arows, const int* __restrict__ acols,
    const float* __restrict__ avals, int annz, int nchA, int* __restrict__ tailA,
    uint2* __restrict__ auxA,
    const int* __restrict__ srows, const int* __restrict__ scols,
    const float* __restrict__ svals, int snnz, int* __restrict__ tailS,
    uint2* __restrict__ auxS)
{
    __shared__ int hcnt[NBIN], hoff[NBIN], hcur[NBIN], hbase[NBIN];
    __shared__ int sR[BCHUNK];
    __shared__ unsigned sK[BCHUNK], sV[BCHUNK];
    const int* rows; const int* cols; const float* vals; int nnz; int* tail;
    uint2* aux; int chunk;
    if ((int)blockIdx.x < nchA) {
        rows = arows; cols = acols; vals = avals; nnz = annz; tail = tailA;
        aux = auxA; chunk = blockIdx.x;
    } else {
        rows = srows; cols = scols; vals = svals; nnz = snnz; tail = tailS;
        aux = auxS; chunk = blockIdx.x - nchA;
    }
    int begE = chunk * BCHUNK;
    int cnt = nnz - begE; if (cnt > BCHUNK) cnt = BCHUNK;
    int t = threadIdx.x;
    if (t < NBIN) hcnt[t] = 0;
    __syncthreads();
    int r[8]; unsigned k[8], v[8];
    for (int q = 0; q < 8; ++q) {
        int idx = t + q * 256;
        if (idx < cnt) {
            int e = begE + idx;
            int rr = ntl(rows + e);
            int cc = ntl(cols + e);
            float vv = ntlf(vals + e);
            r[q] = rr;
            k[q] = ((unsigned)(rr & (RB - 1)) << 17) | (unsigned)cc;
            v[q] = __float_as_uint(vv);
            atomicAdd(&hcnt[rr >> RSHIFT], 1);
        }
    }
    __syncthreads();
    if (t == 0) {
        int run = 0;
        for (int b = 0; b < NBIN; ++b) { hoff[b] = run; hcur[b] = run; run += hcnt[b]; }
    }
    __syncthreads();
    for (int q = 0; q < 8; ++q) {
        int idx = t + q * 256;
        if (idx < cnt) {
            int b = r[q] >> RSHIFT;
            int pos = atomicAdd(&hcur[b], 1);
            sR[pos] = r[q]; sK[pos] = k[q]; sV[pos] = v[q];
        }
    }
    __syncthreads();
    if (t < NBIN && hcnt[t] > 0) hbase[t] = atomicAdd(&tail[t], hcnt[t]);
    __syncthreads();
    for (int idx = t; idx < cnt; idx += 256) {
        int b = sR[idx] >> RSHIFT;
        int g = hbase[b] + (idx - hoff[b]);
        aux[g] = make_uint2(sK[idx], sV[idx]);
    }
}

// One block: bucket counts (tail - slotbase) -> exclusive scan -> pack bases.
__global__ void cnt_scan(const int* __restrict__ tailA, int* __restrict__ bbaseA,
                         int* __restrict__ ptrA,
                         const int* __restrict__ tailS, int* __restrict__ bbaseS,
                         int* __restrict__ ptrS) {
    if (threadIdx.x == 0) {
        int run = 0;
        for (int b = 0; b < KA; ++b) { bbaseA[b] = run; run += tailA[b] - b * SLOT; }
        bbaseA[KA] = run; ptrA[N_NODES] = run;
        run = 0;
        for (int b = 0; b < KS; ++b) { bbaseS[b] = run; run += tailS[b] - b * SLOT; }
        bbaseS[KS] = run; ptrS[USER_NUM] = run;
    }
}

// 2 blocks per coarse bucket (row halves of 512). Hist+scan own half,
// count lower half total (for half 1's pack base), scatter own rows only.
__global__ void __launch_bounds__(512) bucket_scatter_half(
    const uint2* __restrict__ auxA, const int* __restrict__ tailA,
    const int* __restrict__ bbaseA, int* __restrict__ ptrA, int2* __restrict__ packA,
    const uint2* __restrict__ auxS, const int* __restrict__ tailS,
    const int* __restrict__ bbaseS, int* __restrict__ ptrS, int2* __restrict__ packS)
{
    __shared__ int cur[512];
    __shared__ int wsum[8];
    __shared__ int lowsum;
    const uint2* aux; const int* tail; const int* bbase; int* ptr; int2* pack;
    int b, half, n;
    int id = blockIdx.x;
    if (id < 2 * KA) {
        aux = auxA; tail = tailA; bbase = bbaseA; ptr = ptrA; pack = packA;
        b = id >> 1; half = id & 1; n = N_NODES;
    } else {
        id -= 2 * KA;
        aux = auxS; tail = tailS; bbase = bbaseS; ptr = ptrS; pack = packS;
        b = id >> 1; half = id & 1; n = USER_NUM;
    }
    int rowbase = (b << RSHIFT) + half * 512;
    int nrows = n - rowbase; if (nrows > 512) nrows = 512; if (nrows < 0) nrows = 0;
    int segb = b * SLOT, sege = tail[b];
    int t = threadIdx.x;
    cur[t] = 0;
    if (t == 0) lowsum = 0;
    __syncthreads();
    int other = 0;
    for (int idx = segb + t; idx < sege; idx += 512) {
        unsigned rl = aux[idx].x >> 17;
        if ((int)(rl >> 9) == half) atomicAdd(&cur[rl & 511], 1);
        else if (half == 1) other++;
    }
    if (half == 1) {   // reduce count of lower-half entries
        for (int m = 1; m < 64; m <<= 1) other += __shfl_xor(other, m, 64);
        if ((t & 63) == 0) atomicAdd(&lowsum, other);
    }
    __syncthreads();
    int a0 = cur[t];
    int lane = t & 63, wid = t >> 6;
    int s = a0;
    for (int off = 1; off < 64; off <<= 1) {
        int u = __shfl_up(s, off, 64);
        if (lane >= off) s += u;
    }
    if (lane == 63) wsum[wid] = s;
    __syncthreads();
    if (wid == 0) {
        int w = (lane < 8) ? wsum[lane] : 0;
        for (int off = 1; off < 8; off <<= 1) {
            int u = __shfl_up(w, off, 64);
            if (lane >= off) w += u;
        }
        if (lane < 8) wsum[lane] = w;
    }
    __syncthreads();
    int wbase = (wid > 0) ? wsum[wid - 1] : 0;
    int pbase = bbase[b] + (half ? lowsum : 0);
    int base = pbase + wbase + s - a0;
    cur[t] = base;
    if (t < nrows) ptr[rowbase + t] = base;
    __syncthreads();
    for (int idx = segb + t; idx < sege; idx += 512) {
        uint2 e = ntl2u(aux + idx);
        unsigned rl = e.x >> 17;
        if ((int)(rl >> 9) == half) {
            int pos = atomicAdd(&cur[rl & 511], 1);
            pack[pos] = make_int2((int)(e.x & 0x1FFFFu), (int)e.y);
        }
    }
}

__device__ __forceinline__ void gacc(float (&acc)[8], float v, uint4 u) {
    float f0, f1, f2, f3, f4, f5, f6, f7;
    bf2x(u.x, f0, f1); bf2x(u.y, f2, f3); bf2x(u.z, f4, f5); bf2x(u.w, f6, f7);
    acc[0] += v * f0; acc[1] += v * f1; acc[2] += v * f2; acc[3] += v * f3;
    acc[4] += v * f4; acc[5] += v * f5; acc[6] += v * f6; acc[7] += v * f7;
}
__device__ __forceinline__ void reduce8(float (&acc)[8]) {
    for (int m = 8; m < 64; m <<= 1)
        for (int k = 0; k < 8; ++k)
            acc[k] += __shfl_xor(acc[k], m, 64);
}
__device__ __forceinline__ uint4 pack8(const float (&acc)[8]) {
    uint4 o;
    o.x = f2bf(acc[0]) | (f2bf(acc[1]) << 16);
    o.y = f2bf(acc[2]) | (f2bf(acc[3]) << 16);
    o.z = f2bf(acc[4]) | (f2bf(acc[5]) << 16);
    o.w = f2bf(acc[6]) | (f2bf(acc[7]) << 16);
    return o;
}

__global__ void spmm_s(const int* __restrict__ ptr, const int2* __restrict__ pack,
                       const uint4* __restrict__ ego8, uint4* __restrict__ hu8) {
    int r = blockIdx.x * (blockDim.x >> 6) + (threadIdx.x >> 6);
    if (r >= USER_NUM) return;
    int lane = threadIdx.x & 63;
    int g = lane >> 3, li = lane & 7;
    int beg = ptr[r], end = ptr[r + 1];
    float acc[8] = {0, 0, 0, 0, 0, 0, 0, 0};
    int j = beg + g;
    for (; j + 8 < end; j += 16) {
        int2 p0 = pack[j];
        int2 p1 = pack[j + 8];
        uint4 x0 = ego8[p0.x * 8 + li];
        uint4 x1 = ego8[p1.x * 8 + li];
        gacc(acc, __int_as_float(p0.y), x0);
        gacc(acc, __int_as_float(p1.y), x1);
    }
    if (j < end) {
        int2 p = pack[j];
        gacc(acc, __int_as_float(p.y), ego8[p.x * 8 + li]);
    }
    reduce8(acc);
    if (g == 0) {
        uint4 e = ego8[r * 8 + li];
        float f0, f1;
        bf2x(e.x, f0, f1); acc[0] += f0; acc[1] += f1;
        bf2x(e.y, f0, f1); acc[2] += f0; acc[3] += f1;
        bf2x(e.z, f0, f1); acc[4] += f0; acc[5] += f1;
        bf2x(e.w, f0, f1); acc[6] += f0; acc[7] += f1;
        hu8[r * 8 + li] = pack8(acc);
    }
}

__global__ void spmm_adj(const int* __restrict__ ptr, const int2* __restrict__ pack,
                         const uint4* __restrict__ hu8, const uint4* __restrict__ ego8,
                         uint4* __restrict__ next8) {
    int r = blockIdx.x * (blockDim.x >> 6) + (threadIdx.x >> 6);
    if (r >= N_NODES) return;
    int lane = threadIdx.x & 63;
    int g = lane >> 3, li = lane & 7;
    int beg = ptr[r], end = ptr[r + 1];
    float acc[8] = {0, 0, 0, 0, 0, 0, 0, 0};
    int j = beg + g;
    for (; j + 8 < end; j += 16) {
        int2 p0 = pack[j];
        int2 p1 = pack[j + 8];
        uint4 x0 = (p0.x < USER_NUM) ? hu8[p0.x * 8 + li] : ego8[p0.x * 8 + li];
        uint4 x1 = (p1.x < USER_NUM) ? hu8[p1.x * 8 + li] : ego8[p1.x * 8 + li];
        gacc(acc, __int_as_float(p0.y), x0);
        gacc(acc, __int_as_float(p1.y), x1);
    }
    if (j < end) {
        int2 p = pack[j];
        uint4 x = (p.x < USER_NUM) ? hu8[p.x * 8 + li] : ego8[p.x * 8 + li];
        gacc(acc, __int_as_float(p.y), x);
    }
    reduce8(acc);
    if (g == 0) next8[r * 8 + li] = pack8(acc);
}

// acc = (inputs_fp32 + e1 + e2 + e3) * 0.25
__global__ void final_sum(const float* __restrict__ user_emb,
                          const float* __restrict__ item_emb,
                          const uint2* __restrict__ e1, const uint2* __restrict__ e2,
                          const uint2* __restrict__ e3, float* __restrict__ acc) {
    int i = blockIdx.x * blockDim.x + threadIdx.x;
    if (i >= TOTAL4) return;
    float4 v = (i < U4) ? reinterpret_cast<const float4*>(user_emb)[i]
                        : reinterpret_cast<const float4*>(item_emb)[i - U4];
    uint2 a = e1[i], b = e2[i], c = e3[i];
    float f0, f1;
    bf2x(a.x, f0, f1); v.x += f0; v.y += f1;
    bf2x(a.y, f0, f1); v.z += f0; v.w += f1;
    bf2x(b.x, f0, f1); v.x += f0; v.y += f1;
    bf2x(b.y, f0, f1); v.z += f0; v.w += f1;
    bf2x(c.x, f0, f1); v.x += f0; v.y += f1;
    bf2x(c.y, f0, f1); v.z += f0; v.w += f1;
    v.x *= 0.25f; v.y *= 0.25f; v.z *= 0.25f; v.w *= 0.25f;
    reinterpret_cast<float4*>(acc)[i] = v;
}

extern "C" void kernel_launch(void* const* d_in, const int* in_sizes, int n_in,
                              void* d_out, int out_size, void* d_ws, size_t ws_size,
                              hipStream_t stream) {
    const float* user_emb = (const float*)d_in[0];
    const float* item_emb = (const float*)d_in[1];
    const int*   adj_rows = (const int*)d_in[2];
    const int*   adj_cols = (const int*)d_in[3];
    const float* adj_vals = (const float*)d_in[4];
    const int*   s_rows   = (const int*)d_in[5];
    const int*   s_cols   = (const int*)d_in[6];
    const float* s_vals   = (const float*)d_in[7];
    const int adj_nnz = in_sizes[2];
    const int s_nnz   = in_sizes[5];

    float* acc = (float*)d_out;

    char* p = (char*)d_ws;
    auto alloc = [&](size_t bytes) { void* q = p; p += (bytes + 255) & ~(size_t)255; return q; };
    unsigned* egoA = (unsigned*)alloc((size_t)TOTAL * 2);
    unsigned* egoB = (unsigned*)alloc((size_t)TOTAL * 2);
    unsigned* egoC = (unsigned*)alloc((size_t)TOTAL * 2);
    unsigned* hu   = (unsigned*)alloc((size_t)USER_NUM * EMB * 2);
    int*   ptrA  = (int*)alloc((size_t)(N_NODES + 1) * 4);
    int2*  packA = (int2*)alloc((size_t)adj_nnz * 8);
    int*   ptrS  = (int*)alloc((size_t)(USER_NUM + 1) * 4);
    int2*  packS = (int2*)alloc((size_t)s_nnz * 8);
    uint2* auxA  = (uint2*)alloc((size_t)KA * SLOT * 8);
    uint2* auxS  = (uint2*)alloc((size_t)KS * SLOT * 8);
    int*   tailA = (int*)alloc(NBIN * 4);
    int*   tailS = (int*)alloc(NBIN * 4);
    int*   bbaseA= (int*)alloc(NBIN * 4);
    int*   bbaseS= (int*)alloc(NBIN * 4);

    const int BLK = 256;
    const int ew_grid = (TOTAL4 + BLK - 1) / BLK;
    const int nchA = (adj_nnz + BCHUNK - 1) / BCHUNK;
    const int nchS = (s_nnz + BCHUNK - 1) / BCHUNK;

    // ---- CSR build ----
    init_tails<<<1, NBIN, 0, stream>>>(tailA, tailS);
    bin_alloc<<<nchA + nchS, 256, 0, stream>>>(
        adj_rows, adj_cols, adj_vals, adj_nnz, nchA, tailA, auxA,
        s_rows, s_cols, s_vals, s_nnz, tailS, auxS);
    cnt_scan<<<1, 64, 0, stream>>>(tailA, bbaseA, ptrA, tailS, bbaseS, ptrS);
    bucket_scatter_half<<<2 * (KA + KS), 512, 0, stream>>>(
        auxA, tailA, bbaseA, ptrA, packA,
        auxS, tailS, bbaseS, ptrS, packS);

    // ---- init ego ----
    init_kernel<<<ew_grid, BLK, 0, stream>>>(user_emb, item_emb, egoA);

    unsigned* bufs[3] = {egoA, egoB, egoC};
    const int s_grid   = (USER_NUM + 3) / 4;
    const int adj_grid = (N_NODES + 3) / 4;

    for (int l = 0; l < N_LAYERS; ++l) {
        unsigned* in  = bufs[l % 3];
        unsigned* out = bufs[(l + 1) % 3];
        spmm_s<<<s_grid, BLK, 0, stream>>>(ptrS, packS, (const uint4*)in, (uint4*)hu);
        spmm_adj<<<adj_grid, BLK, 0, stream>>>(ptrA, packA, (const uint4*)hu,
                                               (const uint4*)in, (uint4*)out);
    }
    // e1=egoB, e2=egoC, e3=egoA
    final_sum<<<ew_grid, BLK, 0, stream>>>(user_emb, item_emb,
                                           (const uint2*)egoB, (const uint2*)egoC,
                                           (const uint2*)egoA, acc);
}